// Round 1
// baseline (1912.558 us; speedup 1.0000x reference)
//
#include <hip/hip_runtime.h>
#include <cstddef>

#define NBATCH 4096
#define NTIME  64
#define NDIM   16
#define NLDIM  64
#define NAUXK  32
#define NAH    128
#define NH     256
#define MROWS  (NBATCH*NTIME)   // 262144
#define DT_C   0.01f
#define EPS_C  1e-5f

__device__ __forceinline__ float lrelu(float x){ return x > 0.f ? x : 0.01f*x; }
__device__ __forceinline__ float dot4(float4 a, float4 b){
    return a.x*b.x + a.y*b.y + a.z*b.z + a.w*b.w;
}

// ---------------- Kernel 1: partial BN stats over all M rows (16 cols) ---------
__global__ __launch_bounds__(256) void k_stats_partial(const float* __restrict__ xs,
                                                       float* __restrict__ part){
    __shared__ float red[256*32];
    float s[16], q[16];
#pragma unroll
    for(int i=0;i<16;i++){ s[i]=0.f; q[i]=0.f; }
    const int rowsPerBlock = MROWS/256;   // 1024
    int r0 = blockIdx.x*rowsPerBlock + threadIdx.x;
    for(int j=0;j<rowsPerBlock/256;j++){  // 4 rows per thread
        const float4* p = (const float4*)(xs + (size_t)(r0 + j*256)*NDIM);
#pragma unroll
        for(int v=0; v<4; v++){
            float4 f = p[v];
            s[v*4+0]+=f.x; q[v*4+0]+=f.x*f.x;
            s[v*4+1]+=f.y; q[v*4+1]+=f.y*f.y;
            s[v*4+2]+=f.z; q[v*4+2]+=f.z*f.z;
            s[v*4+3]+=f.w; q[v*4+3]+=f.w*f.w;
        }
    }
#pragma unroll
    for(int i=0;i<16;i++){ red[threadIdx.x*32+i]=s[i]; red[threadIdx.x*32+16+i]=q[i]; }
    __syncthreads();
    for(int off=128; off>0; off>>=1){
        if(threadIdx.x < off){
#pragma unroll
            for(int i=0;i<32;i++) red[threadIdx.x*32+i] += red[(threadIdx.x+off)*32+i];
        }
        __syncthreads();
    }
    if(threadIdx.x < 32) part[blockIdx.x*32 + threadIdx.x] = red[threadIdx.x];
}

// ---------------- Kernel 2: finalize stats (enc BN affine + x0 norm stats) -----
// stats layout: [0:16]=a_enc, [16:32]=b_enc, [32:48]=m0, [48:64]=istd0
__global__ __launch_bounds__(256) void k_finalize(const float* __restrict__ xs,
                                                  const float* __restrict__ part,
                                                  const float* __restrict__ gamma,
                                                  const float* __restrict__ beta,
                                                  float* __restrict__ stats){
    __shared__ float red[256*32];
    __shared__ float x0tot[32];
    int tid = threadIdx.x;
    // ---- x0 stats: rows xs[b][0][:], b = tid + j*256 ----
    float s[16], q[16];
#pragma unroll
    for(int i=0;i<16;i++){ s[i]=0.f; q[i]=0.f; }
    for(int j=0;j<16;j++){
        int b = tid + j*256;
        const float4* p = (const float4*)(xs + (size_t)b*(NTIME*NDIM));
#pragma unroll
        for(int v=0; v<4; v++){
            float4 f = p[v];
            s[v*4+0]+=f.x; q[v*4+0]+=f.x*f.x;
            s[v*4+1]+=f.y; q[v*4+1]+=f.y*f.y;
            s[v*4+2]+=f.z; q[v*4+2]+=f.z*f.z;
            s[v*4+3]+=f.w; q[v*4+3]+=f.w*f.w;
        }
    }
#pragma unroll
    for(int i=0;i<16;i++){ red[tid*32+i]=s[i]; red[tid*32+16+i]=q[i]; }
    __syncthreads();
    for(int off=128; off>0; off>>=1){
        if(tid < off){
#pragma unroll
            for(int i=0;i<32;i++) red[tid*32+i] += red[(tid+off)*32+i];
        }
        __syncthreads();
    }
    if(tid < 32) x0tot[tid] = red[tid];
    __syncthreads();
    // ---- reduce the 256 encoder partials ----
#pragma unroll
    for(int i=0;i<32;i++) red[tid*32+i] = part[tid*32+i];
    __syncthreads();
    for(int off=128; off>0; off>>=1){
        if(tid < off){
#pragma unroll
            for(int i=0;i<32;i++) red[tid*32+i] += red[(tid+off)*32+i];
        }
        __syncthreads();
    }
    if(tid < 16){
        int i = tid;
        // x0 (no affine)
        float m0 = x0tot[i] / (float)NBATCH;
        float v0 = x0tot[16+i] / (float)NBATCH - m0*m0;
        stats[32+i] = m0;
        stats[48+i] = 1.0f / sqrtf(v0 + EPS_C);
        // encoder BN: xf = x*a + b
        float me = red[i] / (float)MROWS;
        float ve = red[16+i] / (float)MROWS - me*me;
        float a = gamma[i] / sqrtf(ve + EPS_C);
        stats[i]      = a;
        stats[16+i]   = beta[i] - me*a;
    }
}

// ---------------- Kernel 3: aux MLP -> per-(b,k) angles ------------------------
// auxout[b*64 + 2k] = aux0*DT, [b*64+2k+1] = aux1*DT
__global__ __launch_bounds__(256) void k_aux(const float* __restrict__ xs,
                                             const float* __restrict__ stats,
                                             const float* __restrict__ aux_g,
                                             const float* __restrict__ aux_b,
                                             const float* __restrict__ W1,
                                             const float* __restrict__ b1,
                                             const float* __restrict__ W2,
                                             const float* __restrict__ b2,
                                             const float* __restrict__ W3,
                                             const float* __restrict__ sc3,
                                             float* __restrict__ auxout){
    const int k  = blockIdx.x >> 6;
    const int b0 = (blockIdx.x & 63) * 64;
    __shared__ float xa[64*16];     // 4 KB
    __shared__ float hA[64*128];    // 32 KB
    __shared__ float hB[64*128];    // 32 KB
    __shared__ float av[64*2];
    const int tid = threadIdx.x;

    // phase 0: load x0 rows, normalize, per-head affine
    {
        int r = tid >> 2; int i = (tid & 3)*4;
        const float* p = xs + (size_t)(b0+r)*(NTIME*NDIM) + i;
        float4 v = *(const float4*)p;
        float o[4];
        float vv[4] = {v.x, v.y, v.z, v.w};
#pragma unroll
        for(int c=0;c<4;c++){
            float xn = (vv[c] - stats[32+i+c]) * stats[48+i+c];
            o[c] = xn * aux_g[k*16+i+c] + aux_b[k*16+i+c];
        }
        *(float4*)&xa[r*16+i] = make_float4(o[0],o[1],o[2],o[3]);
    }
    __syncthreads();

    // phase 1: h1 = lrelu(xa @ W1^T + b1)  (64 rows x 128 cols)
    {
        int c  = tid & 127;
        int r0 = (tid >> 7) * 32;
        float wrow[16];
        const float* w = W1 + ((size_t)k*NAH + c)*NDIM;
#pragma unroll
        for(int i=0;i<16;i++) wrow[i] = w[i];
        float acc[32];
#pragma unroll
        for(int r=0;r<32;r++) acc[r]=0.f;
#pragma unroll
        for(int r=0;r<32;r++){
            const float4* xr = (const float4*)&xa[(r0+r)*16];
            float4 x0v=xr[0], x1v=xr[1], x2v=xr[2], x3v=xr[3];
            float a = x0v.x*wrow[0]+x0v.y*wrow[1]+x0v.z*wrow[2]+x0v.w*wrow[3]
                    + x1v.x*wrow[4]+x1v.y*wrow[5]+x1v.z*wrow[6]+x1v.w*wrow[7]
                    + x2v.x*wrow[8]+x2v.y*wrow[9]+x2v.z*wrow[10]+x2v.w*wrow[11]
                    + x3v.x*wrow[12]+x3v.y*wrow[13]+x3v.z*wrow[14]+x3v.w*wrow[15];
            acc[r] = a;
        }
        float bb = b1[k*NAH+c];
#pragma unroll
        for(int r=0;r<32;r++) hA[(r0+r)*128+c] = lrelu(acc[r]+bb);
    }
    __syncthreads();

    // phase 2: h2 = lrelu(h1 @ W2^T + b2)
    {
        int c  = tid & 127;
        int r0 = (tid >> 7) * 32;
        float acc[32];
#pragma unroll
        for(int r=0;r<32;r++) acc[r]=0.f;
        const float4* w4 = (const float4*)(W2 + ((size_t)k*NAH + c)*NAH);
#pragma unroll 2
        for(int ii=0; ii<32; ii++){
            float4 w = w4[ii];
#pragma unroll
            for(int r=0;r<32;r++){
                float4 h = *(const float4*)&hA[(r0+r)*128 + ii*4];
                acc[r] += dot4(h, w);
            }
        }
        float bb = b2[k*NAH+c];
#pragma unroll
        for(int r=0;r<32;r++) hB[(r0+r)*128+c] = lrelu(acc[r]+bb);
    }
    __syncthreads();

    // phase 3: aux = (h2 @ W3^T) * scale
    if(tid < 128){
        int r = tid >> 1, c = tid & 1;
        const float4* w4 = (const float4*)(W3 + ((size_t)k*2 + c)*NAH);
        const float4* h4 = (const float4*)&hB[r*128];
        float a = 0.f;
#pragma unroll
        for(int ii=0; ii<32; ii++) a += dot4(h4[ii], w4[ii]);
        av[r*2+c] = a * sc3[k*2+c];
    }
    __syncthreads();
    if(tid < 64){
        float a0 = av[tid*2+0];
        float a1 = av[tid*2+1];
        auxout[(size_t)(b0+tid)*64 + 2*k + 0] = a0 * DT_C;
        auxout[(size_t)(b0+tid)*64 + 2*k + 1] = a1 * DT_C;
    }
}

// ---------------- Kernel 4: fused encoder MLP, writes y = [xs | yenc] ----------
__global__ __launch_bounds__(256) void k_enc(const float* __restrict__ xs,
                                             const float* __restrict__ stats,
                                             const float* __restrict__ W1,
                                             const float* __restrict__ b1,
                                             const float* __restrict__ W2,
                                             const float* __restrict__ b2,
                                             const float* __restrict__ W3,
                                             const float* __restrict__ sc,
                                             float* __restrict__ outy){
    const int m0 = blockIdx.x * 32;
    __shared__ float xt[32*16];     // 2 KB
    __shared__ float hA[32*256];    // 32 KB  (h1, then overwritten with h2)
    const int tid = threadIdx.x;

    // phase 0: load 32 rows, copy raw to y[...,0:16], BN into xt
    if(tid < 128){
        int r = tid >> 2; int i = (tid & 3)*4;
        float4 v = *(const float4*)(xs + (size_t)(m0+r)*NDIM + i);
        *(float4*)(outy + (size_t)(m0+r)*80 + i) = v;
        float4 xn;
        xn.x = v.x*stats[i+0] + stats[16+i+0];
        xn.y = v.y*stats[i+1] + stats[16+i+1];
        xn.z = v.z*stats[i+2] + stats[16+i+2];
        xn.w = v.w*stats[i+3] + stats[16+i+3];
        *(float4*)&xt[r*16+i] = xn;
    }
    __syncthreads();

    // phase 1: h1 (K=16), thread owns column c = tid, all 32 rows
    {
        int c = tid;
        float wrow[16];
        const float* w = W1 + (size_t)c*NDIM;
#pragma unroll
        for(int i=0;i<16;i++) wrow[i]=w[i];
        float acc[32];
#pragma unroll
        for(int r=0;r<32;r++){
            const float4* xr = (const float4*)&xt[r*16];
            float4 x0v=xr[0], x1v=xr[1], x2v=xr[2], x3v=xr[3];
            acc[r] = x0v.x*wrow[0]+x0v.y*wrow[1]+x0v.z*wrow[2]+x0v.w*wrow[3]
                   + x1v.x*wrow[4]+x1v.y*wrow[5]+x1v.z*wrow[6]+x1v.w*wrow[7]
                   + x2v.x*wrow[8]+x2v.y*wrow[9]+x2v.z*wrow[10]+x2v.w*wrow[11]
                   + x3v.x*wrow[12]+x3v.y*wrow[13]+x3v.z*wrow[14]+x3v.w*wrow[15];
        }
        float bb = b1[c];
#pragma unroll
        for(int r=0;r<32;r++) hA[r*256+c] = lrelu(acc[r]+bb);
    }
    __syncthreads();

    // phase 2: h2 (K=256), thread owns column c = tid, all 32 rows
    {
        int c = tid;
        float acc[32];
#pragma unroll
        for(int r=0;r<32;r++) acc[r]=0.f;
        const float4* w4 = (const float4*)(W2 + (size_t)c*NH);
#pragma unroll 2
        for(int ii=0; ii<64; ii++){
            float4 w = w4[ii];
#pragma unroll
            for(int r=0;r<32;r++){
                float4 h = *(const float4*)&hA[r*256 + ii*4];
                acc[r] += dot4(h, w);
            }
        }
        float bb = b2[c];
#pragma unroll
        for(int r=0;r<32;r++) acc[r] = lrelu(acc[r]+bb);
        __syncthreads();              // all h1 reads done
#pragma unroll
        for(int r=0;r<32;r++) hA[r*256+c] = acc[r];   // overwrite with h2
    }
    __syncthreads();

    // phase 3: yenc (K=256, 64 cols), thread: c = tid&63, 8 rows
    {
        int c  = tid & 63;
        int r0 = (tid >> 6) * 8;
        float acc[8];
#pragma unroll
        for(int r=0;r<8;r++) acc[r]=0.f;
        const float4* w4 = (const float4*)(W3 + (size_t)c*NH);
#pragma unroll 4
        for(int ii=0; ii<64; ii++){
            float4 w = w4[ii];
#pragma unroll
            for(int r=0;r<8;r++){
                float4 h = *(const float4*)&hA[(r0+r)*256 + ii*4];
                acc[r] += dot4(h, w);
            }
        }
        float s = sc[c];
#pragma unroll
        for(int r=0;r<8;r++) outy[(size_t)(m0+r0+r)*80 + 16 + c] = acc[r]*s;
    }
}

// ---------------- Kernel 5: closed-form scan -> y_pred -------------------------
__global__ __launch_bounds__(256) void k_pred(const float* __restrict__ xs,
                                              const float* __restrict__ auxbuf,
                                              const float* __restrict__ Cw,
                                              const float* __restrict__ outy,
                                              float* __restrict__ outyp){
    __shared__ float cw[16*64];
    const int tid = threadIdx.x;
    for(int j=tid; j<1024; j+=256) cw[j] = Cw[j];
    __syncthreads();

    int gid = blockIdx.x*256 + tid;     // 0 .. 262143
    int b = gid >> 6;
    int t = gid & 63;
    const float* yb = outy + (size_t)b*(NTIME*80) + 16;   // yenc[b][0][:]
    const float* ab = auxbuf + (size_t)b*64;
    float tt = (float)t;

    float y[64];
#pragma unroll
    for(int k=0;k<32;k++){
        float th0 = ab[2*k+0];            // a0*DT
        float th1 = ab[2*k+1];            // a1*DT
        float scl = __expf(th0*tt);
        float cc  = __cosf(th1*tt)*scl;
        float ss  = __sinf(th1*tt)*scl;
        float2 y01 = *(const float2*)&yb[2*k];
        y[2*k+0] = cc*y01.x - ss*y01.y;
        y[2*k+1] = ss*y01.x + cc*y01.y;
    }

    float* orow = outyp + (size_t)(b*NTIME + t)*80;
    if(t == 0){
        const float4* p = (const float4*)(xs + (size_t)b*(NTIME*NDIM));
#pragma unroll
        for(int i4=0;i4<4;i4++) *(float4*)&orow[i4*4] = p[i4];
    } else {
        for(int i=0;i<16;i++){
            float a = 0.f;
#pragma unroll
            for(int j4=0;j4<16;j4++){
                float4 c4 = *(const float4*)&cw[i*64 + j4*4];
                a += c4.x*y[j4*4+0] + c4.y*y[j4*4+1] + c4.z*y[j4*4+2] + c4.w*y[j4*4+3];
            }
            orow[i] = a;
        }
    }
#pragma unroll
    for(int j4=0;j4<16;j4++){
        *(float4*)&orow[16+j4*4] = make_float4(y[j4*4+0],y[j4*4+1],y[j4*4+2],y[j4*4+3]);
    }
}

// ---------------- host launcher -----------------------------------------------
extern "C" void kernel_launch(void* const* d_in, const int* in_sizes, int n_in,
                              void* d_out, int out_size, void* d_ws, size_t ws_size,
                              hipStream_t stream) {
    const float* xs     = (const float*)d_in[0];
    const float* enc_g  = (const float*)d_in[1];
    const float* enc_bt = (const float*)d_in[2];
    const float* eW1    = (const float*)d_in[3];
    const float* eb1    = (const float*)d_in[4];
    const float* eW2    = (const float*)d_in[5];
    const float* eb2    = (const float*)d_in[6];
    const float* eW3    = (const float*)d_in[7];
    const float* esc    = (const float*)d_in[8];
    const float* ag     = (const float*)d_in[9];
    const float* abt    = (const float*)d_in[10];
    const float* aW1    = (const float*)d_in[11];
    const float* ab1    = (const float*)d_in[12];
    const float* aW2    = (const float*)d_in[13];
    const float* ab2    = (const float*)d_in[14];
    const float* aW3    = (const float*)d_in[15];
    const float* asc    = (const float*)d_in[16];
    const float* Cw     = (const float*)d_in[17];

    float* out   = (float*)d_out;
    float* ws    = (float*)d_ws;
    float* part   = ws;                  // 256*32 = 8192 floats
    float* stats  = ws + 8192;           // 64 floats
    float* auxout = ws + 8192 + 64;      // B*64 = 262144 floats

    float* outy  = out;                            // (B,64,80)
    float* outyp = out + (size_t)NBATCH*NTIME*80;  // (B,64,80)

    k_stats_partial<<<256, 256, 0, stream>>>(xs, part);
    k_finalize<<<1, 256, 0, stream>>>(xs, part, enc_g, enc_bt, stats);
    k_aux<<<NAUXK*64, 256, 0, stream>>>(xs, stats, ag, abt, aW1, ab1, aW2, ab2, aW3, asc, auxout);
    k_enc<<<MROWS/32, 256, 0, stream>>>(xs, stats, eW1, eb1, eW2, eb2, eW3, esc, outy);
    k_pred<<<MROWS/256, 256, 0, stream>>>(xs, auxout, Cw, outy, outyp);
}

// Round 2
// 462.260 us; speedup vs baseline: 4.1374x; 4.1374x over previous
//
#include <hip/hip_runtime.h>
#include <cstddef>

#define NBATCH 4096
#define NTIME  64
#define NDIM   16
#define NLDIM  64
#define NAUXK  32
#define NAH    128
#define NH     256
#define MROWS  (NBATCH*NTIME)   // 262144
#define DT_C   0.01f
#define EPS_C  1e-5f

using short8 = __attribute__((ext_vector_type(8))) short;
using short4v = __attribute__((ext_vector_type(4))) short;
using f32x4 = __attribute__((ext_vector_type(4))) float;

__device__ __forceinline__ float lrelu(float x){ return x > 0.f ? x : 0.01f*x; }
__device__ __forceinline__ float dot4(float4 a, float4 b){
    return a.x*b.x + a.y*b.y + a.z*b.z + a.w*b.w;
}
__device__ __forceinline__ unsigned short f2bf(float f){
    unsigned u = __builtin_bit_cast(unsigned, f);
    u += 0x7fff + ((u>>16)&1u);
    return (unsigned short)(u>>16);
}

// ---------------- Kernel 1: partial BN stats over all M rows (16 cols) ---------
__global__ __launch_bounds__(256) void k_stats_partial(const float* __restrict__ xs,
                                                       float* __restrict__ part){
    __shared__ float red[256*32];
    float s[16], q[16];
#pragma unroll
    for(int i=0;i<16;i++){ s[i]=0.f; q[i]=0.f; }
    const int rowsPerBlock = MROWS/256;   // 1024
    int r0 = blockIdx.x*rowsPerBlock + threadIdx.x;
    for(int j=0;j<rowsPerBlock/256;j++){  // 4 rows per thread
        const float4* p = (const float4*)(xs + (size_t)(r0 + j*256)*NDIM);
#pragma unroll
        for(int v=0; v<4; v++){
            float4 f = p[v];
            s[v*4+0]+=f.x; q[v*4+0]+=f.x*f.x;
            s[v*4+1]+=f.y; q[v*4+1]+=f.y*f.y;
            s[v*4+2]+=f.z; q[v*4+2]+=f.z*f.z;
            s[v*4+3]+=f.w; q[v*4+3]+=f.w*f.w;
        }
    }
#pragma unroll
    for(int i=0;i<16;i++){ red[threadIdx.x*32+i]=s[i]; red[threadIdx.x*32+16+i]=q[i]; }
    __syncthreads();
    for(int off=128; off>0; off>>=1){
        if(threadIdx.x < off){
#pragma unroll
            for(int i=0;i<32;i++) red[threadIdx.x*32+i] += red[(threadIdx.x+off)*32+i];
        }
        __syncthreads();
    }
    if(threadIdx.x < 32) part[blockIdx.x*32 + threadIdx.x] = red[threadIdx.x];
}

// ---------------- Kernel 2: finalize stats (enc BN affine + x0 norm stats) -----
// stats layout: [0:16]=a_enc, [16:32]=b_enc, [32:48]=m0, [48:64]=istd0
__global__ __launch_bounds__(256) void k_finalize(const float* __restrict__ xs,
                                                  const float* __restrict__ part,
                                                  const float* __restrict__ gamma,
                                                  const float* __restrict__ beta,
                                                  float* __restrict__ stats){
    __shared__ float red[256*32];
    __shared__ float x0tot[32];
    int tid = threadIdx.x;
    float s[16], q[16];
#pragma unroll
    for(int i=0;i<16;i++){ s[i]=0.f; q[i]=0.f; }
    for(int j=0;j<16;j++){
        int b = tid + j*256;
        const float4* p = (const float4*)(xs + (size_t)b*(NTIME*NDIM));
#pragma unroll
        for(int v=0; v<4; v++){
            float4 f = p[v];
            s[v*4+0]+=f.x; q[v*4+0]+=f.x*f.x;
            s[v*4+1]+=f.y; q[v*4+1]+=f.y*f.y;
            s[v*4+2]+=f.z; q[v*4+2]+=f.z*f.z;
            s[v*4+3]+=f.w; q[v*4+3]+=f.w*f.w;
        }
    }
#pragma unroll
    for(int i=0;i<16;i++){ red[tid*32+i]=s[i]; red[tid*32+16+i]=q[i]; }
    __syncthreads();
    for(int off=128; off>0; off>>=1){
        if(tid < off){
#pragma unroll
            for(int i=0;i<32;i++) red[tid*32+i] += red[(tid+off)*32+i];
        }
        __syncthreads();
    }
    if(tid < 32) x0tot[tid] = red[tid];
    __syncthreads();
#pragma unroll
    for(int i=0;i<32;i++) red[tid*32+i] = part[tid*32+i];
    __syncthreads();
    for(int off=128; off>0; off>>=1){
        if(tid < off){
#pragma unroll
            for(int i=0;i<32;i++) red[tid*32+i] += red[(tid+off)*32+i];
        }
        __syncthreads();
    }
    if(tid < 16){
        int i = tid;
        float m0 = x0tot[i] / (float)NBATCH;
        float v0 = x0tot[16+i] / (float)NBATCH - m0*m0;
        stats[32+i] = m0;
        stats[48+i] = 1.0f / sqrtf(v0 + EPS_C);
        float me = red[i] / (float)MROWS;
        float ve = red[16+i] / (float)MROWS - me*me;
        float a = gamma[i] / sqrtf(ve + EPS_C);
        stats[i]      = a;
        stats[16+i]   = beta[i] - me*a;
    }
}

// ---------------- Kernel 2.5: weight prep (fp32 -> bf16, chunk-major) ----------
// dst layout (ushort): [0,4096)        W1bf [n(256)][k(16)]
//                      [4096,69632)    W2s  [kt(8)][n(256)][j(32)]
//                      [69632,86016)   W3s  [kt(8)][n(64)][j(32)]
__global__ __launch_bounds__(256) void k_prep(const float* __restrict__ W1,
                                              const float* __restrict__ W2,
                                              const float* __restrict__ W3,
                                              unsigned short* __restrict__ dst){
    int i = blockIdx.x*256 + threadIdx.x;
    float v;
    if(i < 4096){ v = W1[i]; }
    else if(i < 69632){
        int e = i - 4096; int kt = e>>13, n = (e>>5)&255, j = e&31;
        v = W2[n*256 + kt*32 + j];
    } else if(i < 86016){
        int e = i - 69632; int kt = e>>11, n = (e>>5)&63, j = e&31;
        v = W3[n*256 + kt*32 + j];
    } else return;
    dst[i] = f2bf(v);
}

// ---------------- Kernel 3: aux MLP (unchanged fp32) ---------------------------
__global__ __launch_bounds__(256) void k_aux(const float* __restrict__ xs,
                                             const float* __restrict__ stats,
                                             const float* __restrict__ aux_g,
                                             const float* __restrict__ aux_b,
                                             const float* __restrict__ W1,
                                             const float* __restrict__ b1,
                                             const float* __restrict__ W2,
                                             const float* __restrict__ b2,
                                             const float* __restrict__ W3,
                                             const float* __restrict__ sc3,
                                             float* __restrict__ auxout){
    const int k  = blockIdx.x >> 6;
    const int b0 = (blockIdx.x & 63) * 64;
    __shared__ float xa[64*16];
    __shared__ float hA[64*128];
    __shared__ float hB[64*128];
    __shared__ float av[64*2];
    const int tid = threadIdx.x;

    {
        int r = tid >> 2; int i = (tid & 3)*4;
        const float* p = xs + (size_t)(b0+r)*(NTIME*NDIM) + i;
        float4 v = *(const float4*)p;
        float o[4];
        float vv[4] = {v.x, v.y, v.z, v.w};
#pragma unroll
        for(int c=0;c<4;c++){
            float xn = (vv[c] - stats[32+i+c]) * stats[48+i+c];
            o[c] = xn * aux_g[k*16+i+c] + aux_b[k*16+i+c];
        }
        *(float4*)&xa[r*16+i] = make_float4(o[0],o[1],o[2],o[3]);
    }
    __syncthreads();

    {
        int c  = tid & 127;
        int r0 = (tid >> 7) * 32;
        float wrow[16];
        const float* w = W1 + ((size_t)k*NAH + c)*NDIM;
#pragma unroll
        for(int i=0;i<16;i++) wrow[i] = w[i];
        float acc[32];
#pragma unroll
        for(int r=0;r<32;r++){
            const float4* xr = (const float4*)&xa[(r0+r)*16];
            float4 x0v=xr[0], x1v=xr[1], x2v=xr[2], x3v=xr[3];
            acc[r] = x0v.x*wrow[0]+x0v.y*wrow[1]+x0v.z*wrow[2]+x0v.w*wrow[3]
                   + x1v.x*wrow[4]+x1v.y*wrow[5]+x1v.z*wrow[6]+x1v.w*wrow[7]
                   + x2v.x*wrow[8]+x2v.y*wrow[9]+x2v.z*wrow[10]+x2v.w*wrow[11]
                   + x3v.x*wrow[12]+x3v.y*wrow[13]+x3v.z*wrow[14]+x3v.w*wrow[15];
        }
        float bb = b1[k*NAH+c];
#pragma unroll
        for(int r=0;r<32;r++) hA[(r0+r)*128+c] = lrelu(acc[r]+bb);
    }
    __syncthreads();

    {
        int c  = tid & 127;
        int r0 = (tid >> 7) * 32;
        float acc[32];
#pragma unroll
        for(int r=0;r<32;r++) acc[r]=0.f;
        const float4* w4 = (const float4*)(W2 + ((size_t)k*NAH + c)*NAH);
#pragma unroll 2
        for(int ii=0; ii<32; ii++){
            float4 w = w4[ii];
#pragma unroll
            for(int r=0;r<32;r++){
                float4 h = *(const float4*)&hA[(r0+r)*128 + ii*4];
                acc[r] += dot4(h, w);
            }
        }
        float bb = b2[k*NAH+c];
#pragma unroll
        for(int r=0;r<32;r++) hB[(r0+r)*128+c] = lrelu(acc[r]+bb);
    }
    __syncthreads();

    if(tid < 128){
        int r = tid >> 1, c = tid & 1;
        const float4* w4 = (const float4*)(W3 + ((size_t)k*2 + c)*NAH);
        const float4* h4 = (const float4*)&hB[r*128];
        float a = 0.f;
#pragma unroll
        for(int ii=0; ii<32; ii++) a += dot4(h4[ii], w4[ii]);
        av[r*2+c] = a * sc3[k*2+c];
    }
    __syncthreads();
    if(tid < 64){
        float a0 = av[tid*2+0];
        float a1 = av[tid*2+1];
        auxout[(size_t)(b0+tid)*64 + 2*k + 0] = a0 * DT_C;
        auxout[(size_t)(b0+tid)*64 + 2*k + 1] = a1 * DT_C;
    }
}

// ---------------- Kernel 4: MFMA encoder MLP -----------------------------------
// 64 rows/block, 4 waves x 16 rows. h in swizzled LDS (idx ^ (row&7)<<3).
// Weights staged per K-chunk from chunk-major bf16 buffers (T14 split staging).
__global__ __launch_bounds__(256,3) void k_enc_mfma(const float* __restrict__ xs,
                                                    const float* __restrict__ stats,
                                                    const unsigned short* __restrict__ W1bf,
                                                    const float* __restrict__ b1,
                                                    const unsigned short* __restrict__ W2s,
                                                    const float* __restrict__ b2,
                                                    const unsigned short* __restrict__ W3s,
                                                    const float* __restrict__ esc,
                                                    float* __restrict__ outy){
    __shared__ unsigned short xa[4][16*16];    // 2 KB
    __shared__ unsigned short hb[4][16*256];   // 32 KB, XOR-swizzled
    __shared__ unsigned short wb[8192];        // 16 KB weight chunk

    const int tid  = threadIdx.x;
    const int w    = tid >> 6;
    const int lane = tid & 63;
    const int g    = lane >> 4;
    const int arow = lane & 15;
    const int m0   = blockIdx.x * 64;
    const int mrow0 = m0 + w*16;

    // ---- phase 0: load 16 rows (this wave), passthrough + BN->bf16 into xa ----
    {
        int r = lane >> 2, c4 = (lane & 3)*4;
        float4 v = *(const float4*)(xs + (size_t)(mrow0 + r)*NDIM + c4);
        *(float4*)(outy + (size_t)(mrow0 + r)*80 + c4) = v;
        float o0 = v.x*stats[c4+0] + stats[16+c4+0];
        float o1 = v.y*stats[c4+1] + stats[16+c4+1];
        float o2 = v.z*stats[c4+2] + stats[16+c4+2];
        float o3 = v.w*stats[c4+3] + stats[16+c4+3];
        short4v p;
        p[0]=(short)f2bf(o0); p[1]=(short)f2bf(o1); p[2]=(short)f2bf(o2); p[3]=(short)f2bf(o3);
        *(short4v*)&xa[w][r*16 + c4] = p;
    }
    __syncthreads();

    // ---- layer 1: h1 = lrelu(xn @ W1^T + b1), K=16 (lanes>=32 zero) ----------
    {
        short8 afr = {0,0,0,0,0,0,0,0};
        if(lane < 32) afr = *(const short8*)&xa[w][arow*16 + g*8];
#pragma unroll
        for(int nt=0; nt<16; nt++){
            short8 bfr = {0,0,0,0,0,0,0,0};
            if(lane < 32) bfr = *(const short8*)&W1bf[(nt*16 + arow)*16 + g*8];
            f32x4 a = {0.f,0.f,0.f,0.f};
            a = __builtin_amdgcn_mfma_f32_16x16x32_bf16(afr, bfr, a, 0, 0, 0);
            int c = nt*16 + arow;
            float bb = b1[c];
#pragma unroll
            for(int r=0;r<4;r++){
                int row = g*4 + r;
                float hv = lrelu(a[r] + bb);
                hb[w][(row*256 + c) ^ ((row&7)<<3)] = f2bf(hv);
            }
        }
    }
    __syncthreads();

    // ---- layer 2: h2 = lrelu(h1 @ W2^T + b2), K=256, kt chunks of 32 ---------
    f32x4 acc[16];
#pragma unroll
    for(int i=0;i<16;i++) acc[i] = (f32x4){0.f,0.f,0.f,0.f};

    const short8* w2v = (const short8*)W2s;    // granule view (8 ushorts)
    short8* wbv = (short8*)wb;
    short8 stg[4];
    // stage chunk 0
#pragma unroll
    for(int q=0;q<4;q++) stg[q] = w2v[q*256 + tid];
#pragma unroll
    for(int q=0;q<4;q++) wbv[q*256 + tid] = stg[q];
    __syncthreads();

    for(int kt=0; kt<8; kt++){
        if(kt < 7){
#pragma unroll
            for(int q=0;q<4;q++) stg[q] = w2v[(kt+1)*1024 + q*256 + tid];
        }
        short8 afr = *(const short8*)&hb[w][(arow*256 + kt*32 + g*8) ^ ((arow&7)<<3)];
#pragma unroll
        for(int nt=0; nt<16; nt++){
            short8 bfr = *(const short8*)&wb[(nt*16 + arow)*32 + g*8];
            acc[nt] = __builtin_amdgcn_mfma_f32_16x16x32_bf16(afr, bfr, acc[nt], 0, 0, 0);
        }
        __syncthreads();
        if(kt < 7){
#pragma unroll
            for(int q=0;q<4;q++) wbv[q*256 + tid] = stg[q];
            __syncthreads();
        }
    }

    // ---- h2 writeback over h1 + stage W3 chunk 0 (T14) -----------------------
    const short8* w3v = (const short8*)W3s;
    short8 stg3 = w3v[tid];
#pragma unroll
    for(int nt=0; nt<16; nt++){
        int c = nt*16 + arow;
        float bb = b2[c];
#pragma unroll
        for(int r=0;r<4;r++){
            int row = g*4 + r;
            float hv = lrelu(acc[nt][r] + bb);
            hb[w][(row*256 + c) ^ ((row&7)<<3)] = f2bf(hv);
        }
    }
    wbv[tid] = stg3;
    __syncthreads();

    // ---- layer 3: yenc = (h2 @ W3^T) * esc, N=64 ----------------------------
    f32x4 acc3[4];
#pragma unroll
    for(int i=0;i<4;i++) acc3[i] = (f32x4){0.f,0.f,0.f,0.f};

    for(int kt=0; kt<8; kt++){
        if(kt < 7) stg3 = w3v[(kt+1)*256 + tid];
        short8 afr = *(const short8*)&hb[w][(arow*256 + kt*32 + g*8) ^ ((arow&7)<<3)];
#pragma unroll
        for(int nt=0; nt<4; nt++){
            short8 bfr = *(const short8*)&wb[(nt*16 + arow)*32 + g*8];
            acc3[nt] = __builtin_amdgcn_mfma_f32_16x16x32_bf16(afr, bfr, acc3[nt], 0, 0, 0);
        }
        __syncthreads();
        if(kt < 7){
            wbv[tid] = stg3;
            __syncthreads();
        }
    }

#pragma unroll
    for(int nt=0; nt<4; nt++){
        int c = nt*16 + arow;
        float s = esc[c];
#pragma unroll
        for(int r=0;r<4;r++){
            int row = g*4 + r;
            outy[(size_t)(mrow0 + row)*80 + 16 + c] = acc3[nt][r]*s;
        }
    }
}

// ---------------- Kernel 5: closed-form scan -> y_pred -------------------------
__global__ __launch_bounds__(256) void k_pred(const float* __restrict__ xs,
                                              const float* __restrict__ auxbuf,
                                              const float* __restrict__ Cw,
                                              const float* __restrict__ outy,
                                              float* __restrict__ outyp){
    __shared__ float cw[16*64];
    const int tid = threadIdx.x;
    for(int j=tid; j<1024; j+=256) cw[j] = Cw[j];
    __syncthreads();

    int gid = blockIdx.x*256 + tid;
    int b = gid >> 6;
    int t = gid & 63;
    const float* yb = outy + (size_t)b*(NTIME*80) + 16;
    const float* ab = auxbuf + (size_t)b*64;
    float tt = (float)t;

    float y[64];
#pragma unroll
    for(int k=0;k<32;k++){
        float th0 = ab[2*k+0];
        float th1 = ab[2*k+1];
        float scl = __expf(th0*tt);
        float cc  = __cosf(th1*tt)*scl;
        float ss  = __sinf(th1*tt)*scl;
        float2 y01 = *(const float2*)&yb[2*k];
        y[2*k+0] = cc*y01.x - ss*y01.y;
        y[2*k+1] = ss*y01.x + cc*y01.y;
    }

    float* orow = outyp + (size_t)(b*NTIME + t)*80;
    if(t == 0){
        const float4* p = (const float4*)(xs + (size_t)b*(NTIME*NDIM));
#pragma unroll
        for(int i4=0;i4<4;i4++) *(float4*)&orow[i4*4] = p[i4];
    } else {
        for(int i=0;i<16;i++){
            float a = 0.f;
#pragma unroll
            for(int j4=0;j4<16;j4++){
                float4 c4 = *(const float4*)&cw[i*64 + j4*4];
                a += c4.x*y[j4*4+0] + c4.y*y[j4*4+1] + c4.z*y[j4*4+2] + c4.w*y[j4*4+3];
            }
            orow[i] = a;
        }
    }
#pragma unroll
    for(int j4=0;j4<16;j4++){
        *(float4*)&orow[16+j4*4] = make_float4(y[j4*4+0],y[j4*4+1],y[j4*4+2],y[j4*4+3]);
    }
}

// ---------------- host launcher -----------------------------------------------
extern "C" void kernel_launch(void* const* d_in, const int* in_sizes, int n_in,
                              void* d_out, int out_size, void* d_ws, size_t ws_size,
                              hipStream_t stream) {
    const float* xs     = (const float*)d_in[0];
    const float* enc_g  = (const float*)d_in[1];
    const float* enc_bt = (const float*)d_in[2];
    const float* eW1    = (const float*)d_in[3];
    const float* eb1    = (const float*)d_in[4];
    const float* eW2    = (const float*)d_in[5];
    const float* eb2    = (const float*)d_in[6];
    const float* eW3    = (const float*)d_in[7];
    const float* esc    = (const float*)d_in[8];
    const float* ag     = (const float*)d_in[9];
    const float* abt    = (const float*)d_in[10];
    const float* aW1    = (const float*)d_in[11];
    const float* ab1    = (const float*)d_in[12];
    const float* aW2    = (const float*)d_in[13];
    const float* ab2    = (const float*)d_in[14];
    const float* aW3    = (const float*)d_in[15];
    const float* asc    = (const float*)d_in[16];
    const float* Cw     = (const float*)d_in[17];

    float* out   = (float*)d_out;
    float* ws    = (float*)d_ws;
    float* part   = ws;                  // 8192 floats
    float* stats  = ws + 8192;           // 64 floats
    float* auxout = ws + 8192 + 64;      // 262144 floats
    unsigned short* wbf = (unsigned short*)(ws + 8192 + 64 + 262144);
    unsigned short* W1bf = wbf;          // 4096 ushorts
    unsigned short* W2s  = wbf + 4096;   // 65536 ushorts
    unsigned short* W3s  = wbf + 69632;  // 16384 ushorts

    float* outy  = out;                            // (B,64,80)
    float* outyp = out + (size_t)NBATCH*NTIME*80;  // (B,64,80)

    k_prep<<<336, 256, 0, stream>>>(eW1, eW2, eW3, wbf);
    k_stats_partial<<<256, 256, 0, stream>>>(xs, part);
    k_finalize<<<1, 256, 0, stream>>>(xs, part, enc_g, enc_bt, stats);
    k_aux<<<NAUXK*64, 256, 0, stream>>>(xs, stats, ag, abt, aW1, ab1, aW2, ab2, aW3, asc, auxout);
    k_enc_mfma<<<MROWS/64, 256, 0, stream>>>(xs, stats, W1bf, eb1, W2s, eb2, W3s, esc, outy);
    k_pred<<<MROWS/256, 256, 0, stream>>>(xs, auxout, Cw, outy, outyp);
}

// Round 4
// 214.631 us; speedup vs baseline: 8.9109x; 2.1537x over previous
//
#include <hip/hip_runtime.h>
#include <cstddef>

#define NBATCH 4096
#define NTIME  64
#define NDIM   16
#define NLDIM  64
#define NAUXK  32
#define NAH    128
#define NH     256
#define MROWS  (NBATCH*NTIME)   // 262144
#define DT_C   0.01f
#define EPS_C  1e-5f

using short8 = __attribute__((ext_vector_type(8))) short;
using short4v = __attribute__((ext_vector_type(4))) short;
using f32x4 = __attribute__((ext_vector_type(4))) float;

__device__ __forceinline__ float lrelu(float x){ return x > 0.f ? x : 0.01f*x; }
__device__ __forceinline__ unsigned short f2bf(float f){
    unsigned u = __builtin_bit_cast(unsigned, f);
    u += 0x7fff + ((u>>16)&1u);
    return (unsigned short)(u>>16);
}

// ---------------- Kernel 1: partial BN stats over all M rows (16 cols) ---------
__global__ __launch_bounds__(256) void k_stats_partial(const float* __restrict__ xs,
                                                       float* __restrict__ part){
    __shared__ float red[256*32];
    float s[16], q[16];
#pragma unroll
    for(int i=0;i<16;i++){ s[i]=0.f; q[i]=0.f; }
    const int rowsPerBlock = MROWS/256;   // 1024
    int r0 = blockIdx.x*rowsPerBlock + threadIdx.x;
    for(int j=0;j<rowsPerBlock/256;j++){
        const float4* p = (const float4*)(xs + (size_t)(r0 + j*256)*NDIM);
#pragma unroll
        for(int v=0; v<4; v++){
            float4 f = p[v];
            s[v*4+0]+=f.x; q[v*4+0]+=f.x*f.x;
            s[v*4+1]+=f.y; q[v*4+1]+=f.y*f.y;
            s[v*4+2]+=f.z; q[v*4+2]+=f.z*f.z;
            s[v*4+3]+=f.w; q[v*4+3]+=f.w*f.w;
        }
    }
#pragma unroll
    for(int i=0;i<16;i++){ red[threadIdx.x*32+i]=s[i]; red[threadIdx.x*32+16+i]=q[i]; }
    __syncthreads();
    for(int off=128; off>0; off>>=1){
        if(threadIdx.x < off){
#pragma unroll
            for(int i=0;i<32;i++) red[threadIdx.x*32+i] += red[(threadIdx.x+off)*32+i];
        }
        __syncthreads();
    }
    if(threadIdx.x < 32) part[blockIdx.x*32 + threadIdx.x] = red[threadIdx.x];
}

// ---------------- Kernel 2: finalize stats -------------------------------------
// stats layout: [0:16]=a_enc, [16:32]=b_enc, [32:48]=m0, [48:64]=istd0
__global__ __launch_bounds__(256) void k_finalize(const float* __restrict__ xs,
                                                  const float* __restrict__ part,
                                                  const float* __restrict__ gamma,
                                                  const float* __restrict__ beta,
                                                  float* __restrict__ stats){
    __shared__ float red[256*32];
    __shared__ float x0tot[32];
    int tid = threadIdx.x;
    float s[16], q[16];
#pragma unroll
    for(int i=0;i<16;i++){ s[i]=0.f; q[i]=0.f; }
    for(int j=0;j<16;j++){
        int b = tid + j*256;
        const float4* p = (const float4*)(xs + (size_t)b*(NTIME*NDIM));
#pragma unroll
        for(int v=0; v<4; v++){
            float4 f = p[v];
            s[v*4+0]+=f.x; q[v*4+0]+=f.x*f.x;
            s[v*4+1]+=f.y; q[v*4+1]+=f.y*f.y;
            s[v*4+2]+=f.z; q[v*4+2]+=f.z*f.z;
            s[v*4+3]+=f.w; q[v*4+3]+=f.w*f.w;
        }
    }
#pragma unroll
    for(int i=0;i<16;i++){ red[tid*32+i]=s[i]; red[tid*32+16+i]=q[i]; }
    __syncthreads();
    for(int off=128; off>0; off>>=1){
        if(tid < off){
#pragma unroll
            for(int i=0;i<32;i++) red[tid*32+i] += red[(tid+off)*32+i];
        }
        __syncthreads();
    }
    if(tid < 32) x0tot[tid] = red[tid];
    __syncthreads();
#pragma unroll
    for(int i=0;i<32;i++) red[tid*32+i] = part[tid*32+i];
    __syncthreads();
    for(int off=128; off>0; off>>=1){
        if(tid < off){
#pragma unroll
            for(int i=0;i<32;i++) red[tid*32+i] += red[(tid+off)*32+i];
        }
        __syncthreads();
    }
    if(tid < 16){
        int i = tid;
        float m0 = x0tot[i] / (float)NBATCH;
        float v0 = x0tot[16+i] / (float)NBATCH - m0*m0;
        stats[32+i] = m0;
        stats[48+i] = 1.0f / sqrtf(v0 + EPS_C);
        float me = red[i] / (float)MROWS;
        float ve = red[16+i] / (float)MROWS - me*me;
        float a = gamma[i] / sqrtf(ve + EPS_C);
        stats[i]      = a;
        stats[16+i]   = beta[i] - me*a;
    }
}

// ---------------- Kernel 2.5: weight prep (fp32 -> bf16, chunk-major) ----------
// dst layout (ushort):
//   [0,4096)          enc W1bf [n(256)][k(16)]
//   [4096,69632)      enc W2s  [kt(8)][n(256)][j(32)]
//   [69632,86016)     enc W3s  [kt(8)][n(64)][j(32)]
//   [86016,151552)    aux W1s  [k(32)][n(128)][c(16)]   (BN gamma folded in)
//   [151552,675840)   aux W2s  [k(32)][kt(4)][n(128)][j(32)]
//   [675840,741376)   aux W3s  [k(32)][kt(4)][n(16)][j(32)]  (n>=2 zero-padded)
__global__ __launch_bounds__(256) void k_prep(const float* __restrict__ W1,
                                              const float* __restrict__ W2,
                                              const float* __restrict__ W3,
                                              const float* __restrict__ ag,
                                              const float* __restrict__ aW1,
                                              const float* __restrict__ aW2,
                                              const float* __restrict__ aW3,
                                              unsigned short* __restrict__ dst){
    int i = blockIdx.x*256 + threadIdx.x;
    float v;
    if(i < 4096){ v = W1[i]; }
    else if(i < 69632){
        int e = i - 4096; int kt = e>>13, n = (e>>5)&255, j = e&31;
        v = W2[n*256 + kt*32 + j];
    } else if(i < 86016){
        int e = i - 69632; int kt = e>>11, n = (e>>5)&63, j = e&31;
        v = W3[n*256 + kt*32 + j];
    } else if(i < 151552){
        int e = i - 86016; int k = e>>11, n = (e>>4)&127, c = e&15;
        v = aW1[(k*128+n)*16 + c] * ag[k*16+c];
    } else if(i < 675840){
        int e = i - 151552; int k = e>>14, kt = (e>>12)&3, n = (e>>5)&127, j = e&31;
        v = aW2[(k*128+n)*128 + kt*32 + j];
    } else if(i < 741376){
        int e = i - 675840; int k = e>>11, kt = (e>>9)&3, n = (e>>5)&15, j = e&31;
        v = (n < 2) ? aW3[(k*2+n)*128 + kt*32 + j] : 0.f;
    } else return;
    dst[i] = f2bf(v);
}

// ---------------- Kernel 2.6: aux bias fold: b1' = b1 + W1 @ beta --------------
__global__ __launch_bounds__(256) void k_prep_auxb(const float* __restrict__ aW1,
                                                   const float* __restrict__ ab1,
                                                   const float* __restrict__ abt,
                                                   float* __restrict__ b1p){
    int i = blockIdx.x*256 + threadIdx.x;   // 0..4095
    if(i >= 4096) return;
    int k = i>>7, n = i&127;
    const float* wr = aW1 + (size_t)(k*128+n)*16;
    const float* bt = abt + k*16;
    float a = ab1[i];
#pragma unroll
    for(int c=0;c<16;c++) a += wr[c]*bt[c];
    b1p[i] = a;
}

// ---------------- Kernel 3: MFMA aux MLP ---------------------------------------
// grid: [k(32)][tile(64)]; 64 rows/block, 4 waves x 16 rows.
__global__ __launch_bounds__(256,4) void k_aux_mfma(const float* __restrict__ xs,
                                                    const float* __restrict__ stats,
                                                    const unsigned short* __restrict__ W1s,
                                                    const float* __restrict__ b1p,
                                                    const unsigned short* __restrict__ W2s,
                                                    const float* __restrict__ ab2,
                                                    const unsigned short* __restrict__ W3s,
                                                    const float* __restrict__ asc,
                                                    float* __restrict__ auxout){
    __shared__ unsigned short xa[4][256];    // 2 KB
    __shared__ unsigned short hb[4][2048];   // 16 KB, XOR-swizzled
    __shared__ unsigned short wb[4096];      // 8 KB  W2 K-chunk
    __shared__ unsigned short wb3[2048];     // 4 KB  all of W3 (padded)

    const int tid  = threadIdx.x;
    const int w    = tid >> 6;
    const int lane = tid & 63;
    const int g    = lane >> 4;
    const int arow = lane & 15;
    const int k    = blockIdx.x >> 6;
    const int b0   = (blockIdx.x & 63) * 64;
    const int r0   = b0 + w*16;

    const unsigned short* w1h = W1s + (size_t)k*2048;
    const short8* w2v = (const short8*)(W2s + (size_t)k*16384);
    const short8* w3v = (const short8*)(W3s + (size_t)k*2048);
    const float* b1h = b1p + k*128;
    const float* b2h = ab2 + k*128;
    short8* wbv = (short8*)wb;

    // ---- phase 0: load x0 rows, normalize -> bf16; stage W3 + W2 chunk 0 ------
    {
        int r = lane >> 2, c4 = (lane & 3)*4;
        float4 v = *(const float4*)(xs + (size_t)(r0 + r)*(NTIME*NDIM) + c4);
        short4v p;
        p[0]=(short)f2bf((v.x - stats[32+c4+0])*stats[48+c4+0]);
        p[1]=(short)f2bf((v.y - stats[32+c4+1])*stats[48+c4+1]);
        p[2]=(short)f2bf((v.z - stats[32+c4+2])*stats[48+c4+2]);
        p[3]=(short)f2bf((v.w - stats[32+c4+3])*stats[48+c4+3]);
        *(short4v*)&xa[w][r*16 + c4] = p;
    }
    ((short8*)wb3)[tid] = w3v[tid];   // 256 granules = all of W3 (FIX: was tid<128)
    {
        short8 s0 = w2v[tid], s1 = w2v[256 + tid];
        wbv[tid] = s0; wbv[256 + tid] = s1;
    }
    __syncthreads();

    // ---- layer 1: h1 = lrelu(xn @ W1'^T + b1'), K=16 (lanes>=32 zero) ---------
    {
        short8 afr = {0,0,0,0,0,0,0,0};
        if(lane < 32) afr = *(const short8*)&xa[w][arow*16 + g*8];
        f32x4 acc1[8];
#pragma unroll
        for(int nt=0; nt<8; nt++){
            short8 bfr = {0,0,0,0,0,0,0,0};
            if(lane < 32) bfr = *(const short8*)&w1h[(nt*16 + arow)*16 + g*8];
            f32x4 z = {0.f,0.f,0.f,0.f};
            acc1[nt] = __builtin_amdgcn_mfma_f32_16x16x32_bf16(afr, bfr, z, 0, 0, 0);
        }
#pragma unroll
        for(int nt=0; nt<8; nt++){
            int c = nt*16 + arow;
            float bb = b1h[c];
#pragma unroll
            for(int r=0;r<4;r++){
                int row = g*4 + r;
                hb[w][(row*128 + c) ^ ((row&7)<<3)] = f2bf(lrelu(acc1[nt][r] + bb));
            }
        }
    }
    __syncthreads();

    // ---- layer 2: h2 = lrelu(h1 @ W2^T + b2), K=128, 4 chunks of 32 -----------
    f32x4 acc2[8];
#pragma unroll
    for(int i=0;i<8;i++) acc2[i] = (f32x4){0.f,0.f,0.f,0.f};

    short8 stg0, stg1;
    for(int kt=0; kt<4; kt++){
        if(kt < 3){ stg0 = w2v[(kt+1)*512 + tid]; stg1 = w2v[(kt+1)*512 + 256 + tid]; }
        short8 afr = *(const short8*)&hb[w][(arow*128 + kt*32 + g*8) ^ ((arow&7)<<3)];
#pragma unroll
        for(int nt=0; nt<8; nt++){
            short8 bfr = *(const short8*)&wb[(nt*16 + arow)*32 + g*8];
            acc2[nt] = __builtin_amdgcn_mfma_f32_16x16x32_bf16(afr, bfr, acc2[nt], 0, 0, 0);
        }
        __syncthreads();
        if(kt < 3){
            wbv[tid] = stg0; wbv[256 + tid] = stg1;
            __syncthreads();
        }
    }

    // ---- h2 writeback over h1 -------------------------------------------------
#pragma unroll
    for(int nt=0; nt<8; nt++){
        int c = nt*16 + arow;
        float bb = b2h[c];
#pragma unroll
        for(int r=0;r<4;r++){
            int row = g*4 + r;
            hb[w][(row*128 + c) ^ ((row&7)<<3)] = f2bf(lrelu(acc2[nt][r] + bb));
        }
    }

    // ---- layer 3: aux = (h2 @ W3^T)*scale, N=2 (padded to 16) -----------------
    f32x4 acc3 = {0.f,0.f,0.f,0.f};
#pragma unroll
    for(int kt=0; kt<4; kt++){
        short8 afr = *(const short8*)&hb[w][(arow*128 + kt*32 + g*8) ^ ((arow&7)<<3)];
        short8 bfr = *(const short8*)&wb3[kt*512 + arow*32 + g*8];
        acc3 = __builtin_amdgcn_mfma_f32_16x16x32_bf16(afr, bfr, acc3, 0, 0, 0);
    }
    if(arow < 2){
        float s = asc[k*2 + arow] * DT_C;
#pragma unroll
        for(int r=0;r<4;r++){
            int row = g*4 + r;
            auxout[(size_t)(b0 + w*16 + row)*64 + 2*k + arow] = acc3[r]*s;
        }
    }
}

// ---------------- Kernel 4: MFMA encoder MLP -----------------------------------
__global__ __launch_bounds__(256,3) void k_enc_mfma(const float* __restrict__ xs,
                                                    const float* __restrict__ stats,
                                                    const unsigned short* __restrict__ W1bf,
                                                    const float* __restrict__ b1,
                                                    const unsigned short* __restrict__ W2s,
                                                    const float* __restrict__ b2,
                                                    const unsigned short* __restrict__ W3s,
                                                    const float* __restrict__ esc,
                                                    float* __restrict__ outy){
    __shared__ unsigned short xa[4][16*16];    // 2 KB
    __shared__ unsigned short hb[4][16*256];   // 32 KB, XOR-swizzled
    __shared__ unsigned short wb[8192];        // 16 KB weight chunk

    const int tid  = threadIdx.x;
    const int w    = tid >> 6;
    const int lane = tid & 63;
    const int g    = lane >> 4;
    const int arow = lane & 15;
    const int m0   = blockIdx.x * 64;
    const int mrow0 = m0 + w*16;

    {
        int r = lane >> 2, c4 = (lane & 3)*4;
        float4 v = *(const float4*)(xs + (size_t)(mrow0 + r)*NDIM + c4);
        *(float4*)(outy + (size_t)(mrow0 + r)*80 + c4) = v;
        float o0 = v.x*stats[c4+0] + stats[16+c4+0];
        float o1 = v.y*stats[c4+1] + stats[16+c4+1];
        float o2 = v.z*stats[c4+2] + stats[16+c4+2];
        float o3 = v.w*stats[c4+3] + stats[16+c4+3];
        short4v p;
        p[0]=(short)f2bf(o0); p[1]=(short)f2bf(o1); p[2]=(short)f2bf(o2); p[3]=(short)f2bf(o3);
        *(short4v*)&xa[w][r*16 + c4] = p;
    }
    __syncthreads();

    {
        short8 afr = {0,0,0,0,0,0,0,0};
        if(lane < 32) afr = *(const short8*)&xa[w][arow*16 + g*8];
#pragma unroll
        for(int nt=0; nt<16; nt++){
            short8 bfr = {0,0,0,0,0,0,0,0};
            if(lane < 32) bfr = *(const short8*)&W1bf[(nt*16 + arow)*16 + g*8];
            f32x4 a = {0.f,0.f,0.f,0.f};
            a = __builtin_amdgcn_mfma_f32_16x16x32_bf16(afr, bfr, a, 0, 0, 0);
            int c = nt*16 + arow;
            float bb = b1[c];
#pragma unroll
            for(int r=0;r<4;r++){
                int row = g*4 + r;
                float hv = lrelu(a[r] + bb);
                hb[w][(row*256 + c) ^ ((row&7)<<3)] = f2bf(hv);
            }
        }
    }
    __syncthreads();

    f32x4 acc[16];
#pragma unroll
    for(int i=0;i<16;i++) acc[i] = (f32x4){0.f,0.f,0.f,0.f};

    const short8* w2v = (const short8*)W2s;
    short8* wbv = (short8*)wb;
    short8 stg[4];
#pragma unroll
    for(int q=0;q<4;q++) stg[q] = w2v[q*256 + tid];
#pragma unroll
    for(int q=0;q<4;q++) wbv[q*256 + tid] = stg[q];
    __syncthreads();

    for(int kt=0; kt<8; kt++){
        if(kt < 7){
#pragma unroll
            for(int q=0;q<4;q++) stg[q] = w2v[(kt+1)*1024 + q*256 + tid];
        }
        short8 afr = *(const short8*)&hb[w][(arow*256 + kt*32 + g*8) ^ ((arow&7)<<3)];
#pragma unroll
        for(int nt=0; nt<16; nt++){
            short8 bfr = *(const short8*)&wb[(nt*16 + arow)*32 + g*8];
            acc[nt] = __builtin_amdgcn_mfma_f32_16x16x32_bf16(afr, bfr, acc[nt], 0, 0, 0);
        }
        __syncthreads();
        if(kt < 7){
#pragma unroll
            for(int q=0;q<4;q++) wbv[q*256 + tid] = stg[q];
            __syncthreads();
        }
    }

    const short8* w3v = (const short8*)W3s;
    short8 stg3 = w3v[tid];
#pragma unroll
    for(int nt=0; nt<16; nt++){
        int c = nt*16 + arow;
        float bb = b2[c];
#pragma unroll
        for(int r=0;r<4;r++){
            int row = g*4 + r;
            float hv = lrelu(acc[nt][r] + bb);
            hb[w][(row*256 + c) ^ ((row&7)<<3)] = f2bf(hv);
        }
    }
    wbv[tid] = stg3;
    __syncthreads();

    f32x4 acc3[4];
#pragma unroll
    for(int i=0;i<4;i++) acc3[i] = (f32x4){0.f,0.f,0.f,0.f};

    for(int kt=0; kt<8; kt++){
        if(kt < 7) stg3 = w3v[(kt+1)*256 + tid];
        short8 afr = *(const short8*)&hb[w][(arow*256 + kt*32 + g*8) ^ ((arow&7)<<3)];
#pragma unroll
        for(int nt=0; nt<4; nt++){
            short8 bfr = *(const short8*)&wb[(nt*16 + arow)*32 + g*8];
            acc3[nt] = __builtin_amdgcn_mfma_f32_16x16x32_bf16(afr, bfr, acc3[nt], 0, 0, 0);
        }
        __syncthreads();
        if(kt < 7){
            wbv[tid] = stg3;
            __syncthreads();
        }
    }

#pragma unroll
    for(int nt=0; nt<4; nt++){
        int c = nt*16 + arow;
        float s = esc[c];
#pragma unroll
        for(int r=0;r<4;r++){
            int row = g*4 + r;
            outy[(size_t)(mrow0 + row)*80 + 16 + c] = acc3[nt][r]*s;
        }
    }
}

// ---------------- Kernel 5: closed-form scan -> y_pred -------------------------
__global__ __launch_bounds__(256) void k_pred(const float* __restrict__ xs,
                                              const float* __restrict__ auxbuf,
                                              const float* __restrict__ Cw,
                                              const float* __restrict__ outy,
                                              float* __restrict__ outyp){
    __shared__ float cw[16*64];
    const int tid = threadIdx.x;
    for(int j=tid; j<1024; j+=256) cw[j] = Cw[j];
    __syncthreads();

    int gid = blockIdx.x*256 + tid;
    int b = gid >> 6;
    int t = gid & 63;
    const float* yb = outy + (size_t)b*(NTIME*80) + 16;
    const float* ab = auxbuf + (size_t)b*64;
    float tt = (float)t;

    float y[64];
#pragma unroll
    for(int k=0;k<32;k++){
        float th0 = ab[2*k+0];
        float th1 = ab[2*k+1];
        float scl = __expf(th0*tt);
        float cc  = __cosf(th1*tt)*scl;
        float ss  = __sinf(th1*tt)*scl;
        float2 y01 = *(const float2*)&yb[2*k];
        y[2*k+0] = cc*y01.x - ss*y01.y;
        y[2*k+1] = ss*y01.x + cc*y01.y;
    }

    float* orow = outyp + (size_t)(b*NTIME + t)*80;
    if(t == 0){
        const float4* p = (const float4*)(xs + (size_t)b*(NTIME*NDIM));
#pragma unroll
        for(int i4=0;i4<4;i4++) *(float4*)&orow[i4*4] = p[i4];
    } else {
        for(int i=0;i<16;i++){
            float a = 0.f;
#pragma unroll
            for(int j4=0;j4<16;j4++){
                float4 c4 = *(const float4*)&cw[i*64 + j4*4];
                a += c4.x*y[j4*4+0] + c4.y*y[j4*4+1] + c4.z*y[j4*4+2] + c4.w*y[j4*4+3];
            }
            orow[i] = a;
        }
    }
#pragma unroll
    for(int j4=0;j4<16;j4++){
        *(float4*)&orow[16+j4*4] = make_float4(y[j4*4+0],y[j4*4+1],y[j4*4+2],y[j4*4+3]);
    }
}

// ---------------- host launcher -----------------------------------------------
extern "C" void kernel_launch(void* const* d_in, const int* in_sizes, int n_in,
                              void* d_out, int out_size, void* d_ws, size_t ws_size,
                              hipStream_t stream) {
    const float* xs     = (const float*)d_in[0];
    const float* enc_g  = (const float*)d_in[1];
    const float* enc_bt = (const float*)d_in[2];
    const float* eW1    = (const float*)d_in[3];
    const float* eb1    = (const float*)d_in[4];
    const float* eW2    = (const float*)d_in[5];
    const float* eb2    = (const float*)d_in[6];
    const float* eW3    = (const float*)d_in[7];
    const float* esc    = (const float*)d_in[8];
    const float* ag     = (const float*)d_in[9];
    const float* abt    = (const float*)d_in[10];
    const float* aW1    = (const float*)d_in[11];
    const float* ab1    = (const float*)d_in[12];
    const float* aW2    = (const float*)d_in[13];
    const float* ab2    = (const float*)d_in[14];
    const float* aW3    = (const float*)d_in[15];
    const float* asc    = (const float*)d_in[16];
    const float* Cw     = (const float*)d_in[17];

    float* out   = (float*)d_out;
    float* ws    = (float*)d_ws;
    float* part   = ws;                  // 8192 floats
    float* stats  = ws + 8192;           // 64 floats
    float* auxout = ws + 8256;           // 262144 floats
    float* b1p    = ws + 270400;         // 4096 floats
    unsigned short* wbf = (unsigned short*)(ws + 274496);
    unsigned short* W1bf = wbf;           // 4096
    unsigned short* W2s  = wbf + 4096;    // 65536
    unsigned short* W3s  = wbf + 69632;   // 16384
    unsigned short* aW1s = wbf + 86016;   // 65536
    unsigned short* aW2s = wbf + 151552;  // 524288
    unsigned short* aW3s = wbf + 675840;  // 65536

    float* outy  = out;                            // (B,64,80)
    float* outyp = out + (size_t)NBATCH*NTIME*80;  // (B,64,80)

    k_prep<<<2896, 256, 0, stream>>>(eW1, eW2, eW3, ag, aW1, aW2, aW3, wbf);
    k_prep_auxb<<<16, 256, 0, stream>>>(aW1, ab1, abt, b1p);
    k_stats_partial<<<256, 256, 0, stream>>>(xs, part);
    k_finalize<<<1, 256, 0, stream>>>(xs, part, enc_g, enc_bt, stats);
    k_aux_mfma<<<NAUXK*64, 256, 0, stream>>>(xs, stats, aW1s, b1p, aW2s, ab2, aW3s, asc, auxout);
    k_enc_mfma<<<MROWS/64, 256, 0, stream>>>(xs, stats, W1bf, eb1, W2s, eb2, W3s, esc, outy);
    k_pred<<<MROWS/256, 256, 0, stream>>>(xs, auxout, Cw, outy, outyp);
}

// Round 5
// 183.754 us; speedup vs baseline: 10.4082x; 1.1680x over previous
//
#include <hip/hip_runtime.h>
#include <cstddef>

#define NBATCH 4096
#define NTIME  64
#define NDIM   16
#define NLDIM  64
#define NAUXK  32
#define NAH    128
#define NH     256
#define MROWS  (NBATCH*NTIME)   // 262144
#define DT_C   0.01f
#define EPS_C  1e-5f

using short8 = __attribute__((ext_vector_type(8))) short;
using short4v = __attribute__((ext_vector_type(4))) short;
using f32x4 = __attribute__((ext_vector_type(4))) float;

__device__ __forceinline__ float lrelu(float x){ return x > 0.f ? x : 0.01f*x; }
__device__ __forceinline__ float dot4(float4 a, float4 b){
    return a.x*b.x + a.y*b.y + a.z*b.z + a.w*b.w;
}
__device__ __forceinline__ unsigned short f2bf(float f){
    unsigned u = __builtin_bit_cast(unsigned, f);
    u += 0x7fff + ((u>>16)&1u);
    return (unsigned short)(u>>16);
}
// XOR swizzle on ushort index, keyed by row m (bits 3..5 -> byte bits 4..6)
#define HS(m, x) ((x) ^ (((m)&7)<<3))

// ---------------- Kernel 1: partial BN stats over all M rows (16 cols) ---------
__global__ __launch_bounds__(256) void k_stats_partial(const float* __restrict__ xs,
                                                       float* __restrict__ part){
    __shared__ float red[256*33];   // stride 33: conflict-free tree
    float s[16], q[16];
#pragma unroll
    for(int i=0;i<16;i++){ s[i]=0.f; q[i]=0.f; }
    const int rowsPerBlock = MROWS/256;   // 1024
    int r0 = blockIdx.x*rowsPerBlock + threadIdx.x;
    for(int j=0;j<rowsPerBlock/256;j++){
        const float4* p = (const float4*)(xs + (size_t)(r0 + j*256)*NDIM);
#pragma unroll
        for(int v=0; v<4; v++){
            float4 f = p[v];
            s[v*4+0]+=f.x; q[v*4+0]+=f.x*f.x;
            s[v*4+1]+=f.y; q[v*4+1]+=f.y*f.y;
            s[v*4+2]+=f.z; q[v*4+2]+=f.z*f.z;
            s[v*4+3]+=f.w; q[v*4+3]+=f.w*f.w;
        }
    }
#pragma unroll
    for(int i=0;i<16;i++){ red[threadIdx.x*33+i]=s[i]; red[threadIdx.x*33+16+i]=q[i]; }
    __syncthreads();
    for(int off=128; off>0; off>>=1){
        if(threadIdx.x < off){
#pragma unroll
            for(int i=0;i<32;i++) red[threadIdx.x*33+i] += red[(threadIdx.x+off)*33+i];
        }
        __syncthreads();
    }
    if(threadIdx.x < 32) part[blockIdx.x*32 + threadIdx.x] = red[threadIdx.x];
}

// ---------------- Kernel 2: finalize stats -------------------------------------
// stats layout: [0:16]=a_enc, [16:32]=b_enc, [32:48]=m0, [48:64]=istd0
__global__ __launch_bounds__(256) void k_finalize(const float* __restrict__ xs,
                                                  const float* __restrict__ part,
                                                  const float* __restrict__ gamma,
                                                  const float* __restrict__ beta,
                                                  float* __restrict__ stats){
    __shared__ float red[256*33];
    __shared__ float x0tot[32];
    int tid = threadIdx.x;
    float s[16], q[16];
#pragma unroll
    for(int i=0;i<16;i++){ s[i]=0.f; q[i]=0.f; }
    for(int j=0;j<16;j++){
        int b = tid + j*256;
        const float4* p = (const float4*)(xs + (size_t)b*(NTIME*NDIM));
#pragma unroll
        for(int v=0; v<4; v++){
            float4 f = p[v];
            s[v*4+0]+=f.x; q[v*4+0]+=f.x*f.x;
            s[v*4+1]+=f.y; q[v*4+1]+=f.y*f.y;
            s[v*4+2]+=f.z; q[v*4+2]+=f.z*f.z;
            s[v*4+3]+=f.w; q[v*4+3]+=f.w*f.w;
        }
    }
#pragma unroll
    for(int i=0;i<16;i++){ red[tid*33+i]=s[i]; red[tid*33+16+i]=q[i]; }
    __syncthreads();
    for(int off=128; off>0; off>>=1){
        if(tid < off){
#pragma unroll
            for(int i=0;i<32;i++) red[tid*33+i] += red[(tid+off)*33+i];
        }
        __syncthreads();
    }
    if(tid < 32) x0tot[tid] = red[tid];
    __syncthreads();
#pragma unroll
    for(int i=0;i<32;i++) red[tid*33+i] = part[tid*32+i];
    __syncthreads();
    for(int off=128; off>0; off>>=1){
        if(tid < off){
#pragma unroll
            for(int i=0;i<32;i++) red[tid*33+i] += red[(tid+off)*33+i];
        }
        __syncthreads();
    }
    if(tid < 16){
        int i = tid;
        float m0 = x0tot[i] / (float)NBATCH;
        float v0 = x0tot[16+i] / (float)NBATCH - m0*m0;
        stats[32+i] = m0;
        stats[48+i] = 1.0f / sqrtf(v0 + EPS_C);
        float me = red[i] / (float)MROWS;
        float ve = red[16+i] / (float)MROWS - me*me;
        float a = gamma[i] / sqrtf(ve + EPS_C);
        stats[i]      = a;
        stats[16+i]   = beta[i] - me*a;
    }
}

// ---------------- Kernel 2.5: weight prep (fp32 -> bf16, chunk-major) ----------
// dst layout (ushort):
//   [0,4096)          enc W1bf [n(256)][k(16)]
//   [4096,69632)      enc W2s  [kt(8)][n(256)][j(32)]
//   [69632,86016)     enc W3s  [kt(8)][n(64)][j(32)]
//   [86016,151552)    aux W1s  [k(32)][n(128)][c(16)]   (BN gamma folded in)
//   [151552,675840)   aux W2s  [k(32)][kt(4)][n(128)][j(32)]
//   [675840,741376)   aux W3s  [k(32)][kt(4)][n(16)][j(32)]  (n>=2 zero-padded)
__global__ __launch_bounds__(256) void k_prep(const float* __restrict__ W1,
                                              const float* __restrict__ W2,
                                              const float* __restrict__ W3,
                                              const float* __restrict__ ag,
                                              const float* __restrict__ aW1,
                                              const float* __restrict__ aW2,
                                              const float* __restrict__ aW3,
                                              unsigned short* __restrict__ dst){
    int i = blockIdx.x*256 + threadIdx.x;
    float v;
    if(i < 4096){ v = W1[i]; }
    else if(i < 69632){
        int e = i - 4096; int kt = e>>13, n = (e>>5)&255, j = e&31;
        v = W2[n*256 + kt*32 + j];
    } else if(i < 86016){
        int e = i - 69632; int kt = e>>11, n = (e>>5)&63, j = e&31;
        v = W3[n*256 + kt*32 + j];
    } else if(i < 151552){
        int e = i - 86016; int k = e>>11, n = (e>>4)&127, c = e&15;
        v = aW1[(k*128+n)*16 + c] * ag[k*16+c];
    } else if(i < 675840){
        int e = i - 151552; int k = e>>14, kt = (e>>12)&3, n = (e>>5)&127, j = e&31;
        v = aW2[(k*128+n)*128 + kt*32 + j];
    } else if(i < 741376){
        int e = i - 675840; int k = e>>11, kt = (e>>9)&3, n = (e>>5)&15, j = e&31;
        v = (n < 2) ? aW3[(k*2+n)*128 + kt*32 + j] : 0.f;
    } else return;
    dst[i] = f2bf(v);
}

// ---------------- Kernel 2.6: aux bias fold: b1' = b1 + W1 @ beta --------------
__global__ __launch_bounds__(256) void k_prep_auxb(const float* __restrict__ aW1,
                                                   const float* __restrict__ ab1,
                                                   const float* __restrict__ abt,
                                                   float* __restrict__ b1p){
    int i = blockIdx.x*256 + threadIdx.x;   // 0..4095
    if(i >= 4096) return;
    int k = i>>7, n = i&127;
    const float* wr = aW1 + (size_t)(k*128+n)*16;
    const float* bt = abt + k*16;
    float a = ab1[i];
#pragma unroll
    for(int c=0;c<16;c++) a += wr[c]*bt[c];
    b1p[i] = a;
}

// ---------------- Kernel 3: MFMA aux MLP (operand-swapped) ---------------------
// grid: [k(32)][tile(64)]; 64 rows/block, 4 waves x 16 rows.
// D = mfma(A=W, B=h): lane (g,arow) holds D[n=nt*16+g*4+r][m=arow].
__global__ __launch_bounds__(256,4) void k_aux_mfma(const float* __restrict__ xs,
                                                    const float* __restrict__ stats,
                                                    const unsigned short* __restrict__ W1s,
                                                    const float* __restrict__ b1p,
                                                    const unsigned short* __restrict__ W2s,
                                                    const float* __restrict__ ab2,
                                                    const unsigned short* __restrict__ W3s,
                                                    const float* __restrict__ asc,
                                                    float* __restrict__ auxout){
    __shared__ unsigned short xa[4][256];    // 2 KB
    __shared__ unsigned short hb[4][2048];   // 16 KB, XOR-swizzled rows
    __shared__ unsigned short wb[4096];      // 8 KB  W2 K-chunk
    __shared__ unsigned short wb3[2048];     // 4 KB  all of W3 (padded)

    const int tid  = threadIdx.x;
    const int w    = tid >> 6;
    const int lane = tid & 63;
    const int g    = lane >> 4;
    const int arow = lane & 15;
    const int k    = blockIdx.x >> 6;
    const int b0   = (blockIdx.x & 63) * 64;
    const int r0   = b0 + w*16;

    const unsigned short* w1h = W1s + (size_t)k*2048;
    const short8* w2v = (const short8*)(W2s + (size_t)k*16384);
    const short8* w3v = (const short8*)(W3s + (size_t)k*2048);
    const float* b1h = b1p + k*128;
    const float* b2h = ab2 + k*128;
    short8* wbv = (short8*)wb;

    // ---- phase 0: load x0 rows, normalize -> bf16; stage W3 + W2 chunk 0 ------
    {
        int r = lane >> 2, c4 = (lane & 3)*4;
        float4 v = *(const float4*)(xs + (size_t)(r0 + r)*(NTIME*NDIM) + c4);
        short4v p;
        p[0]=(short)f2bf((v.x - stats[32+c4+0])*stats[48+c4+0]);
        p[1]=(short)f2bf((v.y - stats[32+c4+1])*stats[48+c4+1]);
        p[2]=(short)f2bf((v.z - stats[32+c4+2])*stats[48+c4+2]);
        p[3]=(short)f2bf((v.w - stats[32+c4+3])*stats[48+c4+3]);
        *(short4v*)&xa[w][r*16 + c4] = p;
    }
    ((short8*)wb3)[tid] = w3v[tid];
    {
        short8 s0 = w2v[tid], s1 = w2v[256 + tid];
        wbv[tid] = s0; wbv[256 + tid] = s1;
    }
    __syncthreads();

    // ---- layer 1: h1 = lrelu(xn @ W1'^T + b1'), K=16 (lanes>=32 zero) ---------
    {
        short8 bx = {0,0,0,0,0,0,0,0};
        if(lane < 32) bx = *(const short8*)&xa[w][arow*16 + g*8];
#pragma unroll
        for(int nt=0; nt<8; nt++){
            short8 aw = {0,0,0,0,0,0,0,0};
            if(lane < 32) aw = *(const short8*)&w1h[(nt*16 + arow)*16 + g*8];
            f32x4 z = {0.f,0.f,0.f,0.f};
            f32x4 a = __builtin_amdgcn_mfma_f32_16x16x32_bf16(aw, bx, z, 0, 0, 0);
            float4 b4 = *(const float4*)&b1h[nt*16 + g*4];
            short4v p;
            p[0]=(short)f2bf(lrelu(a[0]+b4.x));
            p[1]=(short)f2bf(lrelu(a[1]+b4.y));
            p[2]=(short)f2bf(lrelu(a[2]+b4.z));
            p[3]=(short)f2bf(lrelu(a[3]+b4.w));
            *(short4v*)&hb[w][HS(arow, arow*128 + nt*16 + g*4)] = p;
        }
    }
    __syncthreads();

    // ---- layer 2: h2 = lrelu(h1 @ W2^T + b2), K=128, 4 chunks of 32 -----------
    f32x4 acc2[8];
#pragma unroll
    for(int i=0;i<8;i++) acc2[i] = (f32x4){0.f,0.f,0.f,0.f};

    short8 stg0, stg1;
    for(int kt=0; kt<4; kt++){
        if(kt < 3){ stg0 = w2v[(kt+1)*512 + tid]; stg1 = w2v[(kt+1)*512 + 256 + tid]; }
        short8 bh = *(const short8*)&hb[w][HS(arow, arow*128 + kt*32 + g*8)];
#pragma unroll
        for(int nt=0; nt<8; nt++){
            short8 aw = *(const short8*)&wb[(nt*16 + arow)*32 + g*8];
            acc2[nt] = __builtin_amdgcn_mfma_f32_16x16x32_bf16(aw, bh, acc2[nt], 0, 0, 0);
        }
        __syncthreads();
        if(kt < 3){
            wbv[tid] = stg0; wbv[256 + tid] = stg1;
            __syncthreads();
        }
    }

    // ---- h2 writeback over h1 (b64, conflict-free) ----------------------------
#pragma unroll
    for(int nt=0; nt<8; nt++){
        float4 b4 = *(const float4*)&b2h[nt*16 + g*4];
        short4v p;
        p[0]=(short)f2bf(lrelu(acc2[nt][0]+b4.x));
        p[1]=(short)f2bf(lrelu(acc2[nt][1]+b4.y));
        p[2]=(short)f2bf(lrelu(acc2[nt][2]+b4.z));
        p[3]=(short)f2bf(lrelu(acc2[nt][3]+b4.w));
        *(short4v*)&hb[w][HS(arow, arow*128 + nt*16 + g*4)] = p;
    }

    // ---- layer 3: aux = (h2 @ W3^T)*scale, N=2 (padded to 16) -----------------
    f32x4 acc3 = {0.f,0.f,0.f,0.f};
#pragma unroll
    for(int kt=0; kt<4; kt++){
        short8 bh = *(const short8*)&hb[w][HS(arow, arow*128 + kt*32 + g*8)];
        short8 aw = *(const short8*)&wb3[kt*512 + arow*32 + g*8];
        acc3 = __builtin_amdgcn_mfma_f32_16x16x32_bf16(aw, bh, acc3, 0, 0, 0);
    }
    if(g == 0){
        float2 o;
        o.x = acc3[0] * asc[k*2+0] * DT_C;
        o.y = acc3[1] * asc[k*2+1] * DT_C;
        *(float2*)&auxout[(size_t)(r0 + arow)*64 + 2*k] = o;
    }
}

// ---------------- Kernel 4: MFMA encoder MLP (operand-swapped) -----------------
__global__ __launch_bounds__(256,3) void k_enc_mfma(const float* __restrict__ xs,
                                                    const float* __restrict__ stats,
                                                    const unsigned short* __restrict__ W1bf,
                                                    const float* __restrict__ b1,
                                                    const unsigned short* __restrict__ W2s,
                                                    const float* __restrict__ b2,
                                                    const unsigned short* __restrict__ W3s,
                                                    const float* __restrict__ esc,
                                                    float* __restrict__ outy){
    __shared__ unsigned short xa[4][16*16];    // 2 KB
    __shared__ unsigned short hb[4][16*256];   // 32 KB, XOR-swizzled rows
    __shared__ unsigned short wb[8192];        // 16 KB weight chunk

    const int tid  = threadIdx.x;
    const int w    = tid >> 6;
    const int lane = tid & 63;
    const int g    = lane >> 4;
    const int arow = lane & 15;
    const int m0   = blockIdx.x * 64;
    const int mrow0 = m0 + w*16;

    {
        int r = lane >> 2, c4 = (lane & 3)*4;
        float4 v = *(const float4*)(xs + (size_t)(mrow0 + r)*NDIM + c4);
        *(float4*)(outy + (size_t)(mrow0 + r)*80 + c4) = v;
        float o0 = v.x*stats[c4+0] + stats[16+c4+0];
        float o1 = v.y*stats[c4+1] + stats[16+c4+1];
        float o2 = v.z*stats[c4+2] + stats[16+c4+2];
        float o3 = v.w*stats[c4+3] + stats[16+c4+3];
        short4v p;
        p[0]=(short)f2bf(o0); p[1]=(short)f2bf(o1); p[2]=(short)f2bf(o2); p[3]=(short)f2bf(o3);
        *(short4v*)&xa[w][r*16 + c4] = p;
    }
    __syncthreads();

    // ---- layer 1: h1, K=16 (lanes>=32 zero) -----------------------------------
    {
        short8 bx = {0,0,0,0,0,0,0,0};
        if(lane < 32) bx = *(const short8*)&xa[w][arow*16 + g*8];
#pragma unroll
        for(int nt=0; nt<16; nt++){
            short8 aw = {0,0,0,0,0,0,0,0};
            if(lane < 32) aw = *(const short8*)&W1bf[(nt*16 + arow)*16 + g*8];
            f32x4 z = {0.f,0.f,0.f,0.f};
            f32x4 a = __builtin_amdgcn_mfma_f32_16x16x32_bf16(aw, bx, z, 0, 0, 0);
            float4 b4 = *(const float4*)&b1[nt*16 + g*4];
            short4v p;
            p[0]=(short)f2bf(lrelu(a[0]+b4.x));
            p[1]=(short)f2bf(lrelu(a[1]+b4.y));
            p[2]=(short)f2bf(lrelu(a[2]+b4.z));
            p[3]=(short)f2bf(lrelu(a[3]+b4.w));
            *(short4v*)&hb[w][HS(arow, arow*256 + nt*16 + g*4)] = p;
        }
    }
    __syncthreads();

    // ---- layer 2: h2, K=256, 8 chunks of 32 -----------------------------------
    f32x4 acc[16];
#pragma unroll
    for(int i=0;i<16;i++) acc[i] = (f32x4){0.f,0.f,0.f,0.f};

    const short8* w2v = (const short8*)W2s;
    short8* wbv = (short8*)wb;
    short8 stg[4];
#pragma unroll
    for(int q=0;q<4;q++) stg[q] = w2v[q*256 + tid];
#pragma unroll
    for(int q=0;q<4;q++) wbv[q*256 + tid] = stg[q];
    __syncthreads();

    for(int kt=0; kt<8; kt++){
        if(kt < 7){
#pragma unroll
            for(int q=0;q<4;q++) stg[q] = w2v[(kt+1)*1024 + q*256 + tid];
        }
        short8 bh = *(const short8*)&hb[w][HS(arow, arow*256 + kt*32 + g*8)];
#pragma unroll
        for(int nt=0; nt<16; nt++){
            short8 aw = *(const short8*)&wb[(nt*16 + arow)*32 + g*8];
            acc[nt] = __builtin_amdgcn_mfma_f32_16x16x32_bf16(aw, bh, acc[nt], 0, 0, 0);
        }
        __syncthreads();
        if(kt < 7){
#pragma unroll
            for(int q=0;q<4;q++) wbv[q*256 + tid] = stg[q];
            __syncthreads();
        }
    }

    // ---- h2 writeback over h1 (b64) + stage W3 chunk 0 ------------------------
    const short8* w3v = (const short8*)W3s;
    short8 stg3 = w3v[tid];
#pragma unroll
    for(int nt=0; nt<16; nt++){
        float4 b4 = *(const float4*)&b2[nt*16 + g*4];
        short4v p;
        p[0]=(short)f2bf(lrelu(acc[nt][0]+b4.x));
        p[1]=(short)f2bf(lrelu(acc[nt][1]+b4.y));
        p[2]=(short)f2bf(lrelu(acc[nt][2]+b4.z));
        p[3]=(short)f2bf(lrelu(acc[nt][3]+b4.w));
        *(short4v*)&hb[w][HS(arow, arow*256 + nt*16 + g*4)] = p;
    }
    wbv[tid] = stg3;
    __syncthreads();

    // ---- layer 3: yenc, N=64 --------------------------------------------------
    f32x4 acc3[4];
#pragma unroll
    for(int i=0;i<4;i++) acc3[i] = (f32x4){0.f,0.f,0.f,0.f};

    for(int kt=0; kt<8; kt++){
        if(kt < 7) stg3 = w3v[(kt+1)*256 + tid];
        short8 bh = *(const short8*)&hb[w][HS(arow, arow*256 + kt*32 + g*8)];
#pragma unroll
        for(int nt=0; nt<4; nt++){
            short8 aw = *(const short8*)&wb[(nt*16 + arow)*32 + g*8];
            acc3[nt] = __builtin_amdgcn_mfma_f32_16x16x32_bf16(aw, bh, acc3[nt], 0, 0, 0);
        }
        __syncthreads();
        if(kt < 7){
            wbv[tid] = stg3;
            __syncthreads();
        }
    }

    // ---- epilogue: float4 stores, lane holds 4 consecutive cols of row arow ---
#pragma unroll
    for(int nt=0; nt<4; nt++){
        float4 e4 = *(const float4*)&esc[nt*16 + g*4];
        float4 o;
        o.x = acc3[nt][0]*e4.x;
        o.y = acc3[nt][1]*e4.y;
        o.z = acc3[nt][2]*e4.z;
        o.w = acc3[nt][3]*e4.w;
        *(float4*)&outy[(size_t)(mrow0 + arow)*80 + 16 + nt*16 + g*4] = o;
    }
}

// ---------------- Kernel 5: closed-form scan -> y_pred -------------------------
__global__ __launch_bounds__(256) void k_pred(const float* __restrict__ xs,
                                              const float* __restrict__ auxbuf,
                                              const float* __restrict__ Cw,
                                              const float* __restrict__ outy,
                                              float* __restrict__ outyp){
    __shared__ float cw[16*64];
    const int tid = threadIdx.x;
    for(int j=tid; j<1024; j+=256) cw[j] = Cw[j];
    __syncthreads();

    int gid = blockIdx.x*256 + tid;
    int b = gid >> 6;
    int t = gid & 63;
    const float* yb = outy + (size_t)b*(NTIME*80) + 16;
    const float* ab = auxbuf + (size_t)b*64;
    float tt = (float)t;

    float y[64];
#pragma unroll
    for(int k=0;k<32;k++){
        float th0 = ab[2*k+0];
        float th1 = ab[2*k+1];
        float scl = __expf(th0*tt);
        float cc  = __cosf(th1*tt)*scl;
        float ss  = __sinf(th1*tt)*scl;
        float2 y01 = *(const float2*)&yb[2*k];
        y[2*k+0] = cc*y01.x - ss*y01.y;
        y[2*k+1] = ss*y01.x + cc*y01.y;
    }

    float* orow = outyp + (size_t)(b*NTIME + t)*80;
    if(t == 0){
        const float4* p = (const float4*)(xs + (size_t)b*(NTIME*NDIM));
#pragma unroll
        for(int i4=0;i4<4;i4++) *(float4*)&orow[i4*4] = p[i4];
    } else {
#pragma unroll
        for(int i4=0;i4<4;i4++){
            float o[4];
#pragma unroll
            for(int ii=0;ii<4;ii++){
                int i = i4*4+ii;
                float a = 0.f;
#pragma unroll
                for(int j4=0;j4<16;j4++){
                    float4 c4 = *(const float4*)&cw[i*64 + j4*4];
                    a += c4.x*y[j4*4+0] + c4.y*y[j4*4+1] + c4.z*y[j4*4+2] + c4.w*y[j4*4+3];
                }
                o[ii] = a;
            }
            *(float4*)&orow[i4*4] = make_float4(o[0],o[1],o[2],o[3]);
        }
    }
#pragma unroll
    for(int j4=0;j4<16;j4++){
        *(float4*)&orow[16+j4*4] = make_float4(y[j4*4+0],y[j4*4+1],y[j4*4+2],y[j4*4+3]);
    }
}

// ---------------- host launcher -----------------------------------------------
extern "C" void kernel_launch(void* const* d_in, const int* in_sizes, int n_in,
                              void* d_out, int out_size, void* d_ws, size_t ws_size,
                              hipStream_t stream) {
    const float* xs     = (const float*)d_in[0];
    const float* enc_g  = (const float*)d_in[1];
    const float* enc_bt = (const float*)d_in[2];
    const float* eW1    = (const float*)d_in[3];
    const float* eb1    = (const float*)d_in[4];
    const float* eW2    = (const float*)d_in[5];
    const float* eb2    = (const float*)d_in[6];
    const float* eW3    = (const float*)d_in[7];
    const float* esc    = (const float*)d_in[8];
    const float* ag     = (const float*)d_in[9];
    const float* abt    = (const float*)d_in[10];
    const float* aW1    = (const float*)d_in[11];
    const float* ab1    = (const float*)d_in[12];
    const float* aW2    = (const float*)d_in[13];
    const float* ab2    = (const float*)d_in[14];
    const float* aW3    = (const float*)d_in[15];
    const float* asc    = (const float*)d_in[16];
    const float* Cw     = (const float*)d_in[17];

    float* out   = (float*)d_out;
    float* ws    = (float*)d_ws;
    float* part   = ws;                  // 8192 floats
    float* stats  = ws + 8192;           // 64 floats
    float* auxout = ws + 8256;           // 262144 floats
    float* b1p    = ws + 270400;         // 4096 floats
    unsigned short* wbf = (unsigned short*)(ws + 274496);
    unsigned short* W1bf = wbf;           // 4096
    unsigned short* W2s  = wbf + 4096;    // 65536
    unsigned short* W3s  = wbf + 69632;   // 16384
    unsigned short* aW1s = wbf + 86016;   // 65536
    unsigned short* aW2s = wbf + 151552;  // 524288
    unsigned short* aW3s = wbf + 675840;  // 65536

    float* outy  = out;                            // (B,64,80)
    float* outyp = out + (size_t)NBATCH*NTIME*80;  // (B,64,80)

    k_prep<<<2896, 256, 0, stream>>>(eW1, eW2, eW3, ag, aW1, aW2, aW3, wbf);
    k_prep_auxb<<<16, 256, 0, stream>>>(aW1, ab1, abt, b1p);
    k_stats_partial<<<256, 256, 0, stream>>>(xs, part);
    k_finalize<<<1, 256, 0, stream>>>(xs, part, enc_g, enc_bt, stats);
    k_aux_mfma<<<NAUXK*64, 256, 0, stream>>>(xs, stats, aW1s, b1p, aW2s, ab2, aW3s, asc, auxout);
    k_enc_mfma<<<MROWS/64, 256, 0, stream>>>(xs, stats, W1bf, eb1, W2s, eb2, W3s, esc, outy);
    k_pred<<<MROWS/256, 256, 0, stream>>>(xs, auxout, Cw, outy, outyp);
}